// Round 7
// baseline (301.943 us; speedup 1.0000x reference)
//
#include <hip/hip_runtime.h>

typedef unsigned short u16;
typedef __bf16 bf16x8 __attribute__((ext_vector_type(8)));
typedef float f32x4 __attribute__((ext_vector_type(4)));
typedef u16 u16x8 __attribute__((ext_vector_type(8)));

#define B_    8
#define CIN   512
#define COUT  512
#define KT    5
#define LEN   4096
#define RED_  128
#define KDIM  (KT * CIN)   /* 2560 */
#define XTROWS (LEN + 4)   /* 4100: rows 0,1 and 4098,4099 are zero halo */
#define NLT   (LEN / 32)   /* 128 l-tiles for avg partials */
#define TPAD  72           /* u16 row stride for transpose tile */

__device__ __forceinline__ u16 f2bf(float f) {
    unsigned int u = __float_as_uint(f);
    u += 0x7fffu + ((u >> 16) & 1u);   // RNE
    return (u16)(u >> 16);
}

typedef __attribute__((address_space(1))) void gvoid_t;
typedef __attribute__((address_space(3))) void lvoid_t;
__device__ __forceinline__ void glds16(const u16* g, u16* l) {
    __builtin_amdgcn_global_load_lds((gvoid_t*)g, (lvoid_t*)l, 16, 0, 0);
}

// ---------------- fused: x (fp32 [b][c][l]) -> xt (bf16 [b][l+2][c]) + avg partial sums ----
// (byte-identical to round-4 passing version)
__global__ void xtavg_kernel(const float* __restrict__ x, u16* __restrict__ xt,
                             float* __restrict__ P) {
    __shared__ __align__(16) u16 T[32 * TPAD];
    const int b  = blockIdx.z;
    const int l0 = blockIdx.x * 32;
    const int c0 = blockIdx.y * 64;
    const int tid = threadIdx.x;
    const int lw = tid & 31;        // l within tile
    const int cg = tid >> 5;        // 0..7 channel-group of 8
    const int l  = l0 + lw;
    const int c8 = c0 + cg * 8;

    const float* xp = x + ((size_t)b * CIN + c8) * LEN + l;
    float f[8];
#pragma unroll
    for (int j = 0; j < 8; ++j) f[j] = xp[(size_t)j * LEN];

    unsigned d[4];
#pragma unroll
    for (int j = 0; j < 4; ++j)
        d[j] = __builtin_amdgcn_perm(__float_as_uint(f[2 * j + 1]),
                                     __float_as_uint(f[2 * j]), 0x07060302);
    *(uint4*)&T[lw * TPAD + cg * 8] = make_uint4(d[0], d[1], d[2], d[3]);

    // avg-pool partial sums: reduce over the 32 l-lanes, one plain store per channel
#pragma unroll
    for (int j = 0; j < 8; ++j) {
        float s = f[j];
#pragma unroll
        for (int off = 16; off > 0; off >>= 1) s += __shfl_down(s, off, 32);
        if (lw == 0) P[(size_t)blockIdx.x * (B_ * CIN) + b * CIN + c8 + j] = s;
    }
    __syncthreads();

    // coalesced output: row r (32 rows), 8 lanes x 16 B = 128 B contiguous per row
    const int r = tid >> 3, cc = (tid & 7) * 8;
    *(uint4*)(xt + ((size_t)b * XTROWS + l0 + 2 + r) * CIN + c0 + cc) =
        *(const uint4*)&T[r * TPAD + cc];

    // zero halo rows (full CIN width, written once by the edge blocks)
    if (blockIdx.y == 0 && l0 == 0 && tid < 128)
        *(uint4*)(xt + ((size_t)b * XTROWS + (tid >> 6)) * CIN + (tid & 63) * 8) =
            make_uint4(0, 0, 0, 0);
    if (blockIdx.y == 0 && l0 == LEN - 32 && tid < 128)
        *(uint4*)(xt + ((size_t)b * XTROWS + LEN + 2 + (tid >> 6)) * CIN + (tid & 63) * 8) =
            make_uint4(0, 0, 0, 0);
}

// one attention branch (256 threads): avg from P; h = relu(avg@w1.T+b1); op = sigmoid(h@w2.T+b2)
// op may be global OR LDS (generic address space).
__device__ __forceinline__ void attn_branch(
    int tid, const float* __restrict__ P,
    const float* w1, const float* b1, const float* w2, const float* b2,
    float* op, int od, int b, float* av, float* h) {
#pragma unroll
    for (int half = 0; half < 2; ++half) {
        const int ch = tid + half * 256;
        const float* pp = P + b * CIN + ch;
        float s = 0.f;
#pragma unroll 8
        for (int lt = 0; lt < NLT; ++lt) s += pp[(size_t)lt * (B_ * CIN)];
        av[ch] = s * (1.0f / LEN);
    }
    __syncthreads();
    // layer 1: row = tid>>1 (128 rows), part = tid&1 (half-dot of 256)
    const int row = tid >> 1, part = tid & 1;
    float acc = 0.f;
    const float4* wr = (const float4*)(w1 + (size_t)row * CIN + part * 256);
    const float* ap = av + part * 256;
#pragma unroll 8
    for (int c = 0; c < 64; ++c) {
        float4 w = wr[c];
        acc += ap[4 * c] * w.x + ap[4 * c + 1] * w.y + ap[4 * c + 2] * w.z + ap[4 * c + 3] * w.w;
    }
    acc += __shfl_down(acc, 1, 64);
    if (part == 0) h[row] = fmaxf(acc + b1[row], 0.f);
    __syncthreads();
    // layer 2: one thread per output
    for (int o = tid; o < od; o += 256) {
        float a2 = b2[o];
        const float4* w2r = (const float4*)(w2 + (size_t)o * RED_);
#pragma unroll 8
        for (int j = 0; j < RED_ / 4; ++j) {
            float4 w = w2r[j];
            a2 += h[4 * j] * w.x + h[4 * j + 1] * w.y + h[4 * j + 2] * w.z + h[4 * j + 3] * w.w;
        }
        op[o] = 1.f / (1.f + expf(-a2));
    }
}

// ---- fusedprep (plain launch, 280 blocks x 256 threads, NO cross-block deps) ----
// blocks 0-255 : compute ka locally (4 batches, LDS) then wbgen for 4 o x 4 b
// blocks 256-279: sa/ia/oa attention branches (one per (branch,b))
__global__ void fusedprep_kernel(
    const float* __restrict__ P, const float* __restrict__ weight,
    const float* kw1, const float* kb1, const float* kw2, const float* kb2,
    const float* sw1, const float* sb1, const float* sw2, const float* sb2,
    const float* iw1, const float* ib1, const float* iw2, const float* ib2,
    const float* ow1, const float* ob1, const float* ow2, const float* ob2,
    float* __restrict__ sa, float* __restrict__ ia, float* __restrict__ oa,
    u16* __restrict__ wb) {
    __shared__ float av[CIN];
    __shared__ float h[RED_];
    __shared__ float kv[4 * KT];
    const int tid = threadIdx.x;

    if (blockIdx.x < 256) {
        const int og = (int)blockIdx.x >> 1;          // 0..127 -> o = og*4 + (tid>>6)
        const int b0 = ((int)blockIdx.x & 1) * 4;     // batches b0..b0+3
        // ---- redundant ka for this block's 4 batches (threads 0-4 write kv in layer 2) ----
#pragma unroll 1
        for (int bb = 0; bb < 4; ++bb) {
            attn_branch(tid, P, kw1, kb1, kw2, kb2, &kv[bb * KT], KT, b0 + bb, av, h);
            __syncthreads();
        }
        // ---- wbgen: wb[b, o, k*512+i] = bf16(weight[o,i,k] * ka[b,k]) ----
        const int o  = og * 4 + (tid >> 6);           // [0,512)
        const int i8 = (tid & 63) * 8;
        const float* wp = weight + ((size_t)o * CIN + i8) * KT;   // 40 consecutive floats
        float wv[40];
#pragma unroll
        for (int q = 0; q < 10; ++q) {
            float4 v = ((const float4*)wp)[q];
            wv[4 * q] = v.x; wv[4 * q + 1] = v.y; wv[4 * q + 2] = v.z; wv[4 * q + 3] = v.w;
        }
#pragma unroll
        for (int bb = 0; bb < 4; ++bb) {
            const int b = b0 + bb;
#pragma unroll
            for (int k = 0; k < KT; ++k) {
                const float s = kv[bb * KT + k];
                u16x8 r;
#pragma unroll
                for (int j = 0; j < 8; ++j) r[j] = f2bf(wv[j * KT + k] * s);
                *(u16x8*)(wb + ((size_t)(b * COUT + o)) * KDIM + k * CIN + i8) = r;
            }
        }
    } else {
        const int vb = (int)blockIdx.x - 256;   // 0..23
        const int br = vb >> 3, b = vb & 7;
        const float *w1, *b1, *w2, *b2; float* op; int od;
        if (br == 0)      { w1 = sw1; b1 = sb1; w2 = sw2; b2 = sb2; op = sa + b;        od = 1;    }
        else if (br == 1) { w1 = iw1; b1 = ib1; w2 = iw2; b2 = ib2; op = ia + b * CIN;  od = CIN;  }
        else              { w1 = ow1; b1 = ob1; w2 = ow2; b2 = ob2; op = oa + b * COUT; od = COUT; }
        attn_branch(tid, P, w1, b1, w2, b2, op, od, b, av, h);
    }
}

// ---- main GEMM (byte-identical to round-4 passing version) ----
__global__ __launch_bounds__(256, 2) void gemm_kernel(
    const u16* __restrict__ wb, const u16* __restrict__ xt,
    const float* __restrict__ sa, const float* __restrict__ ia,
    const float* __restrict__ oa, const float* __restrict__ bias,
    float* __restrict__ out) {
    __shared__ __align__(16) u16 As[5 * 128 * 32];   // [tap][o-row][32]  40960 B
    __shared__ __align__(16) u16 Bs[260 * 32];       // [l-row][32]       16640 B
    __shared__ float sm[128], bm[128];

    const int orig = blockIdx.x;                     // 512 workgroups
    const int wg   = (orig & 7) * 64 + (orig >> 3);  // bijective XCD swizzle
    const int l0 = (wg & 15) * 256;
    const int o0 = ((wg >> 4) & 3) * 128;
    const int b  = wg >> 6;
    const int tid = threadIdx.x;

    if (tid < 128) {
        sm[tid] = sa[b] * ia[b * CIN + o0 + tid] * oa[b * COUT + o0 + tid];
        bm[tid] = bias[o0 + tid];
    }

    const int lane = tid & 63;
    const int wave = tid >> 6;
    const int wm = (wave >> 1) * 64;     // o offset of wave-tile
    const int wn = (wave & 1) * 128;     // l offset of wave-tile
    const int lm = lane & 15;
    const int quad = lane >> 4;

    f32x4 acc[4][8];
#pragma unroll
    for (int i = 0; i < 4; ++i)
#pragma unroll
        for (int j = 0; j < 8; ++j) {
            f32x4 zz = {0.f, 0.f, 0.f, 0.f};
            acc[i][j] = zz;
        }

    // A staging map: 4 lanes per o-row, 8 elems each
    const u16* gA = wb + ((size_t)(b * COUT + o0 + (tid >> 2))) * KDIM + (tid & 3) * 8;
    // B staging map: xt rows l0 .. l0+259 (xt row p holds x at l = p-2; halo pre-zeroed)
    const u16* gB = xt + ((size_t)b * XTROWS + l0) * CIN;

#pragma unroll 1
    for (int ic = 0; ic < 16; ++ic) {
        const int i0 = ic * 32;
        // ---- A: 10 DMA stages (5 taps x 2 row-halves) ----
#pragma unroll
        for (int t = 0; t < KT; ++t) {
            glds16(gA + t * 512 + i0, &As[t * 4096 + tid * 8]);
            glds16(gA + (size_t)64 * KDIM + t * 512 + i0, &As[t * 4096 + 2048 + tid * 8]);
        }
        // ---- B: 260 rows x 32 chan = 1040 slots of 16 B, pure DMA ----
#pragma unroll
        for (int r = 0; r < 4; ++r) {
            const int slot = r * 256 + tid;
            glds16(gB + (size_t)(slot >> 2) * CIN + i0 + (slot & 3) * 8, &Bs[slot * 8]);
        }
        if (tid < 16)
            glds16(gB + (size_t)(256 + (tid >> 2)) * CIN + i0 + (tid & 3) * 8,
                   &Bs[(1024 + tid) * 8]);
        __syncthreads();

        // ---- compute: 5 taps x 32 MFMA per wave ----
#pragma unroll
        for (int t = 0; t < KT; ++t) {
            bf16x8 af[4], bfr[8];
#pragma unroll
            for (int f = 0; f < 4; ++f)
                af[f] = *(const bf16x8*)&As[t * 4096 + (wm + f * 16 + lm) * 32 + quad * 8];
#pragma unroll
            for (int f = 0; f < 8; ++f)
                bfr[f] = *(const bf16x8*)&Bs[(wn + f * 16 + lm + t) * 32 + quad * 8];
#pragma unroll
            for (int mt = 0; mt < 4; ++mt)
#pragma unroll
                for (int nt = 0; nt < 8; ++nt)
                    acc[mt][nt] = __builtin_amdgcn_mfma_f32_16x16x32_bf16(
                        af[mt], bfr[nt], acc[mt][nt], 0, 0, 0);
        }
        __syncthreads();
    }

    // epilogue: out = s*acc + bias, C/D layout col=lane&15, row=quad*4+reg
#pragma unroll
    for (int mt = 0; mt < 4; ++mt) {
        const int mb = wm + mt * 16 + quad * 4;
        float sv[4], bv[4];
#pragma unroll
        for (int r = 0; r < 4; ++r) { sv[r] = sm[mb + r]; bv[r] = bm[mb + r]; }
#pragma unroll
        for (int nt = 0; nt < 8; ++nt) {
            const int col = l0 + wn + nt * 16 + lm;
            float* op = out + ((size_t)(b * COUT + o0 + mb)) * LEN + col;
#pragma unroll
            for (int r = 0; r < 4; ++r)
                op[(size_t)r * LEN] = sv[r] * acc[mt][nt][r] + bv[r];
        }
    }
}

extern "C" void kernel_launch(void* const* d_in, const int* in_sizes, int n_in,
                              void* d_out, int out_size, void* d_ws, size_t ws_size,
                              hipStream_t stream) {
    const float* x      = (const float*)d_in[0];
    const float* weight = (const float*)d_in[1];
    const float* bias   = (const float*)d_in[2];
    float* out = (float*)d_out;

    char* ws = (char*)d_ws;
    size_t off = 0;
    auto alloc = [&](size_t bytes) {
        void* p = ws + off;
        off += (bytes + 255) & ~(size_t)255;
        return p;
    };
    u16*   wbuf = (u16*)alloc((size_t)B_ * COUT * KDIM * sizeof(u16));     // 21.0 MB
    u16*   xtb  = (u16*)alloc((size_t)B_ * XTROWS * CIN * sizeof(u16));    // 33.6 MB
    float* Pbuf = (float*)alloc((size_t)NLT * B_ * CIN * sizeof(float));   // 2.0 MB
    float* sa   = (float*)alloc((size_t)B_ * sizeof(float));
    float* ia   = (float*)alloc((size_t)B_ * CIN * sizeof(float));
    float* oa   = (float*)alloc((size_t)B_ * COUT * sizeof(float));

    xtavg_kernel<<<dim3(LEN / 32, CIN / 64, B_), 256, 0, stream>>>(x, xtb, Pbuf);
    fusedprep_kernel<<<280, 256, 0, stream>>>(Pbuf, weight,
        (const float*)d_in[3],  (const float*)d_in[4],  (const float*)d_in[5],  (const float*)d_in[6],
        (const float*)d_in[7],  (const float*)d_in[8],  (const float*)d_in[9],  (const float*)d_in[10],
        (const float*)d_in[11], (const float*)d_in[12], (const float*)d_in[13], (const float*)d_in[14],
        (const float*)d_in[15], (const float*)d_in[16], (const float*)d_in[17], (const float*)d_in[18],
        sa, ia, oa, wbuf);
    gemm_kernel<<<512, 256, 0, stream>>>(wbuf, xtb, sa, ia, oa, bias, out);
}

// Round 8
// 241.151 us; speedup vs baseline: 1.2521x; 1.2521x over previous
//
#include <hip/hip_runtime.h>

typedef unsigned short u16;
typedef __bf16 bf16x8 __attribute__((ext_vector_type(8)));
typedef float f32x4 __attribute__((ext_vector_type(4)));
typedef u16 u16x8 __attribute__((ext_vector_type(8)));

#define B_    8
#define CIN   512
#define COUT  512
#define KT    5
#define LEN   4096
#define RED_  128
#define KDIM  (KT * CIN)   /* 2560 */
#define XTROWS (LEN + 4)   /* 4100: rows 0,1 and 4098,4099 are zero halo */
#define NLT   64           /* l-tiles of 64 for avg partials */

__device__ __forceinline__ u16 f2bf(float f) {
    unsigned int u = __float_as_uint(f);
    u += 0x7fffu + ((u >> 16) & 1u);   // RNE
    return (u16)(u >> 16);
}

typedef __attribute__((address_space(1))) void gvoid_t;
typedef __attribute__((address_space(3))) void lvoid_t;
__device__ __forceinline__ void glds16(const u16* g, u16* l) {
    __builtin_amdgcn_global_load_lds((gvoid_t*)g, (lvoid_t*)l, 16, 0, 0);
}

// ---- x (fp32 [b][c][l]) -> xt (bf16 [b][l+2][c]) + avg partials, 256 B bursts both sides ----
// tile 64 l x 128 c; grid (LEN/64, CIN/128, B) = 2048 blocks x 256 threads.
// reads: float4 along l (256 B/row via 16 lanes); channel-pair packed to u32 in regs (v_perm,
// truncation — numerics identical to prior passing version); LDS transpose u32-granular
// (<=2-way banks, verified); writes: 256 B contiguous per xt row; avg via LDS column sums.
__global__ __launch_bounds__(256) void xtavg_kernel(const float* __restrict__ x,
                                                    u16* __restrict__ xt,
                                                    float* __restrict__ P) {
    __shared__ __align__(16) unsigned Tu[64 * 65];   // [l][c-pair], stride 65  (16.6 KB)
    __shared__ float Fp[64 * 2 * 17];                // [c-pair][ch][lq pad 17] (8.7 KB)
    const int b  = blockIdx.z;
    const int l0 = blockIdx.x * 64;
    const int c0 = blockIdx.y * 128;
    const int tid = threadIdx.x;
    const int lq  = tid & 15;           // l-quad: l = lq*4 .. +3
    const int cpg = tid >> 4;           // c-pair group within pass (0..15)

#pragma unroll
    for (int p = 0; p < 4; ++p) {
        const int cp = p * 16 + cpg;            // 0..63
        const int c  = c0 + cp * 2;
        const float* xa = x + ((size_t)b * CIN + c) * LEN + l0 + lq * 4;
        float4 va = *(const float4*)xa;
        float4 vb = *(const float4*)(xa + LEN);
        // u = (bf16(va), bf16(vb)) packed little-endian: low half = channel c, high = c+1
        unsigned u0 = __builtin_amdgcn_perm(__float_as_uint(vb.x), __float_as_uint(va.x), 0x07060302);
        unsigned u1 = __builtin_amdgcn_perm(__float_as_uint(vb.y), __float_as_uint(va.y), 0x07060302);
        unsigned u2 = __builtin_amdgcn_perm(__float_as_uint(vb.z), __float_as_uint(va.z), 0x07060302);
        unsigned u3 = __builtin_amdgcn_perm(__float_as_uint(vb.w), __float_as_uint(va.w), 0x07060302);
        Tu[(lq * 4 + 0) * 65 + cp] = u0;
        Tu[(lq * 4 + 1) * 65 + cp] = u1;
        Tu[(lq * 4 + 2) * 65 + cp] = u2;
        Tu[(lq * 4 + 3) * 65 + cp] = u3;
        Fp[(cp * 2 + 0) * 17 + lq] = va.x + va.y + va.z + va.w;
        Fp[(cp * 2 + 1) * 17 + lq] = vb.x + vb.y + vb.z + vb.w;
    }
    __syncthreads();

    // xt rows: 4 passes x 16 rows; per row 16 lanes x (4 x b32 -> one 16 B store), 256 B/row
#pragma unroll
    for (int p = 0; p < 4; ++p) {
        const int r  = p * 16 + (tid >> 4);     // l row 0..63
        const int j4 = (tid & 15) * 4;          // uint col 0..60
        unsigned w0 = Tu[r * 65 + j4 + 0];
        unsigned w1 = Tu[r * 65 + j4 + 1];
        unsigned w2 = Tu[r * 65 + j4 + 2];
        unsigned w3 = Tu[r * 65 + j4 + 3];
        *(uint4*)(xt + ((size_t)b * XTROWS + l0 + 2 + r) * CIN + c0 + j4 * 2) =
            make_uint4(w0, w1, w2, w3);
    }
    // avg partials: threads 0..127 own channel c0+tid, sum the 16 lq partials
    if (tid < 128) {
        const float* fp = &Fp[tid * 17];        // (cp*2+ch)*17 == tid*17
        float s = 0.f;
#pragma unroll
        for (int k = 0; k < 16; ++k) s += fp[k];
        P[(size_t)blockIdx.x * (B_ * CIN) + b * CIN + c0 + tid] = s;
    }
    // zero halo rows (full CIN width, once per batch)
    if (blockIdx.y == 0 && blockIdx.x == 0 && tid < 128)
        *(uint4*)(xt + ((size_t)b * XTROWS + (tid >> 6)) * CIN + (tid & 63) * 8) =
            make_uint4(0, 0, 0, 0);
    if (blockIdx.y == 0 && blockIdx.x == (LEN / 64 - 1) && tid < 128)
        *(uint4*)(xt + ((size_t)b * XTROWS + LEN + 2 + (tid >> 6)) * CIN + (tid & 63) * 8) =
            make_uint4(0, 0, 0, 0);
}

// ---------------- attention branches (512 threads), avg reduced from partials ----------------
// (round-4 passing version; NLT now 64)
__global__ void attn_kernel(const float* __restrict__ P,
    const float* kw1, const float* kb1, const float* kw2, const float* kb2,
    const float* sw1, const float* sb1, const float* sw2, const float* sb2,
    const float* iw1, const float* ib1, const float* iw2, const float* ib2,
    const float* ow1, const float* ob1, const float* ow2, const float* ob2,
    float* __restrict__ ka, float* __restrict__ sa,
    float* __restrict__ ia, float* __restrict__ oa) {
    const int br = blockIdx.x >> 3, b = blockIdx.x & 7;
    const float *w1, *b1p, *w2, *b2p; float* op; int od;
    if (br == 0)      { w1 = kw1; b1p = kb1; w2 = kw2; b2p = kb2; op = ka + b * KT;  od = KT;   }
    else if (br == 1) { w1 = sw1; b1p = sb1; w2 = sw2; b2p = sb2; op = sa + b;       od = 1;    }
    else if (br == 2) { w1 = iw1; b1p = ib1; w2 = iw2; b2p = ib2; op = ia + b * CIN; od = CIN;  }
    else              { w1 = ow1; b1p = ob1; w2 = ow2; b2p = ob2; op = oa + b * COUT; od = COUT; }

    __shared__ float av[4 * 132];   // 4 chunks of 128, padded
    __shared__ float h[RED_];
    const int t = threadIdx.x;      // 512 threads
    {
        const float* pp = P + b * CIN + t;
        float ssum = 0.f;
#pragma unroll 8
        for (int lt = 0; lt < NLT; ++lt) ssum += pp[(size_t)lt * (B_ * CIN)];
        av[(t >> 7) * 132 + (t & 127)] = ssum * (1.0f / LEN);
    }
    __syncthreads();

    // layer 1: row = t>>2 (128 rows), part = t&3 (quarter-dot of 128 elems)
    const int row = t >> 2, part = t & 3;
    float acc = 0.f;
    const float4* wr = (const float4*)(w1 + (size_t)row * CIN + part * 128);
    const float* ap = &av[part * 132];
#pragma unroll 8
    for (int c = 0; c < 32; ++c) {
        float4 w = wr[c];
        acc += ap[4 * c] * w.x + ap[4 * c + 1] * w.y + ap[4 * c + 2] * w.z + ap[4 * c + 3] * w.w;
    }
    acc += __shfl_down(acc, 1, 64);
    acc += __shfl_down(acc, 2, 64);
    if (part == 0) h[row] = fmaxf(acc + b1p[row], 0.f);
    __syncthreads();

    // layer 2: one thread per output
    for (int o = t; o < od; o += 512) {
        float a2 = b2p[o];
        const float4* w2r = (const float4*)(w2 + (size_t)o * RED_);
#pragma unroll 8
        for (int j = 0; j < RED_ / 4; ++j) {
            float4 w = w2r[j];
            a2 += h[4 * j] * w.x + h[4 * j + 1] * w.y + h[4 * j + 2] * w.z + h[4 * j + 3] * w.w;
        }
        op[o] = 1.f / (1.f + expf(-a2));
    }
}

// wb[b, o, k*512 + i] = bf16( weight[o,i,k] * ka[b,k] )   (round-4 passing version)
__global__ void wbgen_kernel(const float* __restrict__ w, const float* __restrict__ ka,
                             u16* __restrict__ wb) {
    __shared__ float kv[B_ * KT];
    const int tid = threadIdx.x;                 // 256
    if (tid < B_ * KT) kv[tid] = ka[tid];
    __syncthreads();
    const int o  = (blockIdx.x >> 2) * 4 + (tid >> 6);   // 4 o's per block
    const int b0 = (blockIdx.x & 3) * 2;                 // batches b0, b0+1
    const int i8 = (tid & 63) * 8;

    const float* wp = w + ((size_t)o * CIN + i8) * KT;   // 40 consecutive floats
    float wv[40];
#pragma unroll
    for (int q = 0; q < 10; ++q) {
        float4 v = ((const float4*)wp)[q];
        wv[4 * q] = v.x; wv[4 * q + 1] = v.y; wv[4 * q + 2] = v.z; wv[4 * q + 3] = v.w;
    }
#pragma unroll
    for (int bb = 0; bb < 2; ++bb) {
        const int b = b0 + bb;
#pragma unroll
        for (int k = 0; k < KT; ++k) {
            const float s = kv[b * KT + k];
            u16x8 r;
#pragma unroll
            for (int j = 0; j < 8; ++j) r[j] = f2bf(wv[j * KT + k] * s);
            *(u16x8*)(wb + ((size_t)(b * COUT + o)) * KDIM + k * CIN + i8) = r;
        }
    }
}

// ---- main GEMM (byte-identical to round-4 passing version) ----
__global__ __launch_bounds__(256, 2) void gemm_kernel(
    const u16* __restrict__ wb, const u16* __restrict__ xt,
    const float* __restrict__ sa, const float* __restrict__ ia,
    const float* __restrict__ oa, const float* __restrict__ bias,
    float* __restrict__ out) {
    __shared__ __align__(16) u16 As[5 * 128 * 32];   // [tap][o-row][32]  40960 B
    __shared__ __align__(16) u16 Bs[260 * 32];       // [l-row][32]       16640 B
    __shared__ float sm[128], bm[128];

    const int orig = blockIdx.x;                     // 512 workgroups
    const int wg   = (orig & 7) * 64 + (orig >> 3);  // bijective XCD swizzle
    const int l0 = (wg & 15) * 256;
    const int o0 = ((wg >> 4) & 3) * 128;
    const int b  = wg >> 6;
    const int tid = threadIdx.x;

    if (tid < 128) {
        sm[tid] = sa[b] * ia[b * CIN + o0 + tid] * oa[b * COUT + o0 + tid];
        bm[tid] = bias[o0 + tid];
    }

    const int lane = tid & 63;
    const int wave = tid >> 6;
    const int wm = (wave >> 1) * 64;     // o offset of wave-tile
    const int wn = (wave & 1) * 128;     // l offset of wave-tile
    const int lm = lane & 15;
    const int quad = lane >> 4;

    f32x4 acc[4][8];
#pragma unroll
    for (int i = 0; i < 4; ++i)
#pragma unroll
        for (int j = 0; j < 8; ++j) {
            f32x4 zz = {0.f, 0.f, 0.f, 0.f};
            acc[i][j] = zz;
        }

    // A staging map: 4 lanes per o-row, 8 elems each
    const u16* gA = wb + ((size_t)(b * COUT + o0 + (tid >> 2))) * KDIM + (tid & 3) * 8;
    // B staging map: xt rows l0 .. l0+259 (xt row p holds x at l = p-2; halo pre-zeroed)
    const u16* gB = xt + ((size_t)b * XTROWS + l0) * CIN;

#pragma unroll 1
    for (int ic = 0; ic < 16; ++ic) {
        const int i0 = ic * 32;
        // ---- A: 10 DMA stages (5 taps x 2 row-halves) ----
#pragma unroll
        for (int t = 0; t < KT; ++t) {
            glds16(gA + t * 512 + i0, &As[t * 4096 + tid * 8]);
            glds16(gA + (size_t)64 * KDIM + t * 512 + i0, &As[t * 4096 + 2048 + tid * 8]);
        }
        // ---- B: 260 rows x 32 chan = 1040 slots of 16 B, pure DMA ----
#pragma unroll
        for (int r = 0; r < 4; ++r) {
            const int slot = r * 256 + tid;
            glds16(gB + (size_t)(slot >> 2) * CIN + i0 + (slot & 3) * 8, &Bs[slot * 8]);
        }
        if (tid < 16)
            glds16(gB + (size_t)(256 + (tid >> 2)) * CIN + i0 + (tid & 3) * 8,
                   &Bs[(1024 + tid) * 8]);
        __syncthreads();

        // ---- compute: 5 taps x 32 MFMA per wave ----
#pragma unroll
        for (int t = 0; t < KT; ++t) {
            bf16x8 af[4], bfr[8];
#pragma unroll
            for (int f = 0; f < 4; ++f)
                af[f] = *(const bf16x8*)&As[t * 4096 + (wm + f * 16 + lm) * 32 + quad * 8];
#pragma unroll
            for (int f = 0; f < 8; ++f)
                bfr[f] = *(const bf16x8*)&Bs[(wn + f * 16 + lm + t) * 32 + quad * 8];
#pragma unroll
            for (int mt = 0; mt < 4; ++mt)
#pragma unroll
                for (int nt = 0; nt < 8; ++nt)
                    acc[mt][nt] = __builtin_amdgcn_mfma_f32_16x16x32_bf16(
                        af[mt], bfr[nt], acc[mt][nt], 0, 0, 0);
        }
        __syncthreads();
    }

    // epilogue: out = s*acc + bias, C/D layout col=lane&15, row=quad*4+reg
#pragma unroll
    for (int mt = 0; mt < 4; ++mt) {
        const int mb = wm + mt * 16 + quad * 4;
        float sv[4], bv[4];
#pragma unroll
        for (int r = 0; r < 4; ++r) { sv[r] = sm[mb + r]; bv[r] = bm[mb + r]; }
#pragma unroll
        for (int nt = 0; nt < 8; ++nt) {
            const int col = l0 + wn + nt * 16 + lm;
            float* op = out + ((size_t)(b * COUT + o0 + mb)) * LEN + col;
#pragma unroll
            for (int r = 0; r < 4; ++r)
                op[(size_t)r * LEN] = sv[r] * acc[mt][nt][r] + bv[r];
        }
    }
}

extern "C" void kernel_launch(void* const* d_in, const int* in_sizes, int n_in,
                              void* d_out, int out_size, void* d_ws, size_t ws_size,
                              hipStream_t stream) {
    const float* x      = (const float*)d_in[0];
    const float* weight = (const float*)d_in[1];
    const float* bias   = (const float*)d_in[2];
    float* out = (float*)d_out;

    char* ws = (char*)d_ws;
    size_t off = 0;
    auto alloc = [&](size_t bytes) {
        void* p = ws + off;
        off += (bytes + 255) & ~(size_t)255;
        return p;
    };
    u16*   wbuf = (u16*)alloc((size_t)B_ * COUT * KDIM * sizeof(u16));     // 21.0 MB
    u16*   xtb  = (u16*)alloc((size_t)B_ * XTROWS * CIN * sizeof(u16));    // 33.6 MB
    float* Pbuf = (float*)alloc((size_t)NLT * B_ * CIN * sizeof(float));   // 1.0 MB
    float* ka   = (float*)alloc((size_t)B_ * KT * sizeof(float));
    float* sa   = (float*)alloc((size_t)B_ * sizeof(float));
    float* ia   = (float*)alloc((size_t)B_ * CIN * sizeof(float));
    float* oa   = (float*)alloc((size_t)B_ * COUT * sizeof(float));

    xtavg_kernel<<<dim3(LEN / 64, CIN / 128, B_), 256, 0, stream>>>(x, xtb, Pbuf);
    attn_kernel<<<32, 512, 0, stream>>>(Pbuf,
        (const float*)d_in[3],  (const float*)d_in[4],  (const float*)d_in[5],  (const float*)d_in[6],
        (const float*)d_in[7],  (const float*)d_in[8],  (const float*)d_in[9],  (const float*)d_in[10],
        (const float*)d_in[11], (const float*)d_in[12], (const float*)d_in[13], (const float*)d_in[14],
        (const float*)d_in[15], (const float*)d_in[16], (const float*)d_in[17], (const float*)d_in[18],
        ka, sa, ia, oa);
    wbgen_kernel<<<(COUT / 4) * 4, 256, 0, stream>>>(weight, ka, wbuf);
    gemm_kernel<<<512, 256, 0, stream>>>(wbuf, xtb, sa, ia, oa, bias, out);
}